// Round 5
// baseline (40.571 us; speedup 1.0000x reference)
//
#include <hip/hip_runtime.h>
#include <math.h>

namespace {

constexpr int BLOCK = 256;

typedef float f32x2 __attribute__((ext_vector_type(2)));
typedef float f32x4 __attribute__((ext_vector_type(4)));

constexpr double PI_D = 3.14159265358979323846;
constexpr double RAD = PI_D / 180.0;

// model constants (computed in double at compile time, truncated to f32)
constexpr float KG1 = (float)(-(9.1 * 0.15 + (3.6 + 1.5) * 0.39) * 9.81);   // -32.90274
constexpr float KG2 = (float)(-(3.6 * 0.2 + 1.5 * 0.43) * 9.81);            // -13.39065
constexpr float KC  = (float)(3.6 * 0.39 * 0.2 + 1.5 * 0.39 * 0.43);        // 0.53235
constexpr float M11 = (float)(0.112007 + 9.1 * 0.15 * 0.15 + (3.6 + 1.5) * 0.39 * 0.39); // 1.092467
constexpr float M22 = (float)(0.0591636 + 3.6 * 0.2 * 0.2 + 1.5 * 0.43 * 0.43);          // 0.4805136
constexpr float HALF_PI = (float)(PI_D / 2.0);

// cos(k*(x - phi)) = cos(k*x - k*phi): fused phases
constexpr float PH_VLAT = (float)(0.8 * 100.0 * RAD);
constexpr float PH_BF   = (float)(65.0 * RAD);
constexpr float PH_RFH  = (float)(127.0 * RAD);
constexpr float PH_RFK  = (float)(0.55 * 100.0 * RAD);
constexpr float PH_STH  = (float)(122.0 * RAD);
constexpr float PH_STK  = (float)(85.0 * RAD);
constexpr float PH_IL   = (float)(0.6 * 140.0 * RAD);
constexpr float PH_GM   = (float)(0.75 * 90.0 * RAD);
constexpr float PH_MG   = (float)(0.7 * 50.0 * RAD);

constexpr float LRF_SQ  = (float)(0.39 * 0.39 + 0.03 * 0.03);   // 0.1530
constexpr float LRF_2LH = (float)(2.0 * 0.39 * 0.03);           // 0.0234
constexpr float LRF_BASE = 0.39115214431f;                      // sqrt(0.1530)
constexpr float RKNEE = 0.03f;
constexpr float INV_TACT = (float)(1.0 / 0.12);

__device__ __forceinline__ float blendf(float x) {
    // s = 0.95 * sigmoid(100*(x-0.07)); x*s + (1-s)*0.05
    float t = 100.0f * (x - 0.07f);
    float e = __expf(-t);                              // v_exp_f32
    float s = 0.95f * __builtin_amdgcn_rcpf(1.0f + e); // v_rcp_f32
    return x * s + (1.0f - s) * 0.05f;
}

__global__ __launch_bounds__(BLOCK) void crazyleg_kernel(
    const float* __restrict__ q,
    const float* __restrict__ qd,
    const float* __restrict__ A,
    const float* __restrict__ U,
    float* __restrict__ out,
    int B)
{
    // Wave-local staging: each 64-lane wave stages its own 64 rows of R/L in
    // LDS (output layout, no padding) and flushes them itself -> NO s_barrier.
    //   write stride 14: gcd(14,32)=2 -> 2-way (free, m136); stride 7: odd -> clean
    //   flush: dense ds_read_b128 -> conflict-free
    __shared__ __align__(16) float ldsR[BLOCK * 14];
    __shared__ __align__(16) float ldsL[BLOCK * 7];

    const int tid  = (int)threadIdx.x;
    const int wave = tid >> 6;
    const int lane = tid & 63;
    const int r0   = (int)blockIdx.x * BLOCK;
    const int i    = r0 + tid;

    float* __restrict__ outG  = out;
    float* __restrict__ outC  = out + (size_t)2  * B;
    float* __restrict__ outM  = out + (size_t)6  * B;
    float* __restrict__ outR  = out + (size_t)10 * B;
    float* __restrict__ outL  = out + (size_t)24 * B;
    float* __restrict__ outAd = out + (size_t)31 * B;

    if (i < B) {
        const f32x2 qv  = __builtin_nontemporal_load(
            reinterpret_cast<const f32x2*>(q  + 2 * (size_t)i));
        const f32x2 qdv = __builtin_nontemporal_load(
            reinterpret_cast<const f32x2*>(qd + 2 * (size_t)i));
        const float q0 = qv.x,  q1 = qv.y;
        const float qd0 = qdv.x, qd1 = qdv.y;

        float s0, c0, s01, c01;
        __sincosf(q0, &s0, &c0);          // v_sin_f32 / v_cos_f32
        __sincosf(q0 - q1, &s01, &c01);
        const float s1 = __sinf(q1);

        // --- Gq ---
        f32x2 gv; gv.x = KG1 * s0; gv.y = KG2 * s1;
        *reinterpret_cast<f32x2*>(outG + 2 * (size_t)i) = gv;

        // --- Cmat ---
        const float c12 = -KC * s01 * qd1;
        const float c21 =  KC * s01 * qd0;
        f32x4 cv; cv.x = 0.0f; cv.y = c12; cv.z = c21; cv.w = 0.0f;
        *reinterpret_cast<f32x4*>(outC + 4 * (size_t)i) = cv;

        // --- Mmat ---
        const float m12 = KC * c01;
        f32x4 mv; mv.x = M11; mv.y = m12; mv.z = m12; mv.w = M22;
        *reinterpret_cast<f32x4*>(outM + 4 * (size_t)i) = mv;

        // --- Rmat (stage to LDS, output layout) ---
        const float RVlat = 0.05f  * __cosf(0.8f  * q1 - PH_VLAT);
        const float RBF   = -0.038f * __cosf(q1 - PH_BF);
        const float RRF_h = 0.053f * __cosf(q0 - PH_RFH);
        const float RRF_k = 0.053f * __cosf(0.55f * q1 - PH_RFK);
        const float RST_h = -0.07f * __cosf(q0 - PH_STH);
        const float RST_k = -0.04f * __cosf(q1 - PH_STK);
        const float RIl   = 0.045f * __cosf(0.6f  * q0 - PH_IL);
        const float RGM   = -0.06f * __cosf(0.75f * q0 - PH_GM);
        const float RMG   = -0.038f * __cosf(0.7f  * q1 - PH_MG);

        float* lr = ldsR + (size_t)tid * 14;
        lr[0]  = RIl;   lr[1]  = RGM;   lr[2]  = RRF_h; lr[3]  = RST_h;
        lr[4]  = 0.0f;  lr[5]  = 0.0f;  lr[6]  = 0.0f;
        lr[7]  = 0.0f;  lr[8]  = 0.0f;
        lr[9]  = RRF_k; lr[10] = RST_k; lr[11] = RVlat; lr[12] = RBF; lr[13] = RMG;

        // --- L (stage to LDS, output layout) ---
        const float dq01 = q1 - q0;
        const float LIl  = 0.094f - 0.035f * (q0 - HALF_PI);
        const float LGM  = 0.127f + 0.04f  * (q0 - HALF_PI);
        const float LRF  = 0.06f + __builtin_amdgcn_sqrtf(LRF_SQ + LRF_2LH * c0)
                           - LRF_BASE - RKNEE * dq01;
        const float LST  = 0.055f + 0.05f * (q0 - HALF_PI) + RKNEE * dq01;
        const float Lvl  = 0.046f - RKNEE * dq01;   // 0.046 + RKNEE*(q0-q1)
        const float Lbf  = 0.139f + RKNEE * dq01;
        const float LMG  = 0.055f + RKNEE * dq01;

        float* ll = ldsL + (size_t)tid * 7;
        ll[0] = blendf(LIl);
        ll[1] = blendf(LGM);
        ll[2] = blendf(LRF);
        ll[3] = blendf(LST);
        ll[4] = blendf(Lvl);
        ll[5] = blendf(Lbf);
        ll[6] = blendf(LMG);
    }

    // Same-wave LDS ordering: reads below are program-order after writes above;
    // compiler inserts lgkmcnt waits (aliasing on the same __shared__ arrays).
    __builtin_amdgcn_wave_barrier();

    // --- wave-local vectorized flush (no block barrier) ---
    const int nrows = min(BLOCK, B - r0);
    const int wbase = wave * 64;                      // this wave's first row in block
    const int nw    = min(64, max(0, nrows - wbase)); // rows this wave staged

    if (nw > 0) {
        {
            const int nRe = nw * 14;
            const int nR4 = nRe >> 2;
            const f32x4* s4 = reinterpret_cast<const f32x4*>(ldsR + (size_t)wbase * 14);
            f32x4* d4 = reinterpret_cast<f32x4*>(outR + (size_t)(r0 + wbase) * 14);
            for (int j = lane; j < nR4; j += 64) d4[j] = s4[j];
            for (int e = (nR4 << 2) + lane; e < nRe; e += 64)
                outR[(size_t)(r0 + wbase) * 14 + e] = ldsR[(size_t)wbase * 14 + e];
        }
        {
            const int nLe = nw * 7;
            const int nL4 = nLe >> 2;
            const f32x4* s4 = reinterpret_cast<const f32x4*>(ldsL + (size_t)wbase * 7);
            f32x4* d4 = reinterpret_cast<f32x4*>(outL + (size_t)(r0 + wbase) * 7);
            for (int j = lane; j < nL4; j += 64) d4[j] = s4[j];
            for (int e = (nL4 << 2) + lane; e < nLe; e += 64)
                outL[(size_t)(r0 + wbase) * 7 + e] = ldsL[(size_t)wbase * 7 + e];
        }
    }

    // --- Adot = (U - A) / TACT1, fused elementwise phase (float4) ---
    {
        const long long n = 7LL * B;
        const int n4 = (int)(n >> 2);
        const f32x4* __restrict__ A4 = reinterpret_cast<const f32x4*>(A);
        const f32x4* __restrict__ U4 = reinterpret_cast<const f32x4*>(U);
        f32x4* __restrict__ Ad4 = reinterpret_cast<f32x4*>(outAd);
        const int stride = (int)gridDim.x * BLOCK;
        for (int idx = r0 + tid; idx < n4; idx += stride) {
            const f32x4 a = __builtin_nontemporal_load(A4 + idx);
            const f32x4 u = __builtin_nontemporal_load(U4 + idx);
            f32x4 d = (u - a) * INV_TACT;
            Ad4[idx] = d;   // store stays normal (write-combining through L2)
        }
        // scalar tail (B not multiple of 4)
        for (long long idx = 4LL * n4 + (r0 + tid); idx < n; idx += stride) {
            const float a = __builtin_nontemporal_load(A + idx);
            const float u = __builtin_nontemporal_load(U + idx);
            outAd[idx] = (u - a) * INV_TACT;
        }
    }
}

}  // namespace

extern "C" void kernel_launch(void* const* d_in, const int* in_sizes, int n_in,
                              void* d_out, int out_size, void* d_ws, size_t ws_size,
                              hipStream_t stream) {
    const float* q  = (const float*)d_in[0];
    const float* qd = (const float*)d_in[1];
    const float* A  = (const float*)d_in[2];
    const float* U  = (const float*)d_in[3];
    float* out = (float*)d_out;

    const int B = in_sizes[0] / 2;
    const int grid = (B + BLOCK - 1) / BLOCK;

    hipLaunchKernelGGL(crazyleg_kernel, dim3(grid), dim3(BLOCK), 0, stream,
                       q, qd, A, U, out, B);
}

// Round 6
// 38.453 us; speedup vs baseline: 1.0551x; 1.0551x over previous
//
#include <hip/hip_runtime.h>
#include <math.h>

namespace {

constexpr int BLOCK = 256;

typedef float f32x2 __attribute__((ext_vector_type(2)));
typedef float f32x4 __attribute__((ext_vector_type(4)));

constexpr double PI_D = 3.14159265358979323846;
constexpr double RAD = PI_D / 180.0;

// model constants (computed in double at compile time, truncated to f32)
constexpr float KG1 = (float)(-(9.1 * 0.15 + (3.6 + 1.5) * 0.39) * 9.81);   // -32.90274
constexpr float KG2 = (float)(-(3.6 * 0.2 + 1.5 * 0.43) * 9.81);            // -13.39065
constexpr float KC  = (float)(3.6 * 0.39 * 0.2 + 1.5 * 0.39 * 0.43);        // 0.53235
constexpr float M11 = (float)(0.112007 + 9.1 * 0.15 * 0.15 + (3.6 + 1.5) * 0.39 * 0.39); // 1.092467
constexpr float M22 = (float)(0.0591636 + 3.6 * 0.2 * 0.2 + 1.5 * 0.43 * 0.43);          // 0.4805136
constexpr float HALF_PI = (float)(PI_D / 2.0);

// cos(k*(x - phi)) = cos(k*x - k*phi): fused phases
constexpr float PH_VLAT = (float)(0.8 * 100.0 * RAD);
constexpr float PH_BF   = (float)(65.0 * RAD);
constexpr float PH_RFH  = (float)(127.0 * RAD);
constexpr float PH_RFK  = (float)(0.55 * 100.0 * RAD);
constexpr float PH_STH  = (float)(122.0 * RAD);
constexpr float PH_STK  = (float)(85.0 * RAD);
constexpr float PH_IL   = (float)(0.6 * 140.0 * RAD);
constexpr float PH_GM   = (float)(0.75 * 90.0 * RAD);
constexpr float PH_MG   = (float)(0.7 * 50.0 * RAD);

constexpr float LRF_SQ  = (float)(0.39 * 0.39 + 0.03 * 0.03);   // 0.1530
constexpr float LRF_2LH = (float)(2.0 * 0.39 * 0.03);           // 0.0234
constexpr float LRF_BASE = 0.39115214431f;                      // sqrt(0.1530)
constexpr float RKNEE = 0.03f;
constexpr float INV_TACT = (float)(1.0 / 0.12);

__device__ __forceinline__ float blendf(float x) {
    // s = 0.95 * sigmoid(100*(x-0.07)); x*s + (1-s)*0.05
    float t = 100.0f * (x - 0.07f);
    float e = __expf(-t);                              // v_exp_f32
    float s = 0.95f * __builtin_amdgcn_rcpf(1.0f + e); // v_rcp_f32
    return x * s + (1.0f - s) * 0.05f;
}

__global__ __launch_bounds__(BLOCK) void crazyleg_kernel(
    const float* __restrict__ q,
    const float* __restrict__ qd,
    const float* __restrict__ A,
    const float* __restrict__ U,
    float* __restrict__ out,
    int B)
{
    // Wave-local staging: each 64-lane wave stages its own 64 rows of R/L in
    // LDS (output layout, no padding) and flushes them itself -> NO s_barrier.
    //   write stride 14: gcd(14,32)=2 -> 2-way (free, m136); stride 7: odd -> clean
    //   flush: dense ds_read_b128 -> conflict-free
    // NOTE: no nontemporal hints anywhere — measured +2.3us regression (R5)
    // from nt loads; default cache path wins for streaming on gfx950.
    __shared__ __align__(16) float ldsR[BLOCK * 14];
    __shared__ __align__(16) float ldsL[BLOCK * 7];

    const int tid  = (int)threadIdx.x;
    const int wave = tid >> 6;
    const int lane = tid & 63;
    const int r0   = (int)blockIdx.x * BLOCK;
    const int i    = r0 + tid;

    float* __restrict__ outG  = out;
    float* __restrict__ outC  = out + (size_t)2  * B;
    float* __restrict__ outM  = out + (size_t)6  * B;
    float* __restrict__ outR  = out + (size_t)10 * B;
    float* __restrict__ outL  = out + (size_t)24 * B;
    float* __restrict__ outAd = out + (size_t)31 * B;

    if (i < B) {
        const f32x2 qv  = *reinterpret_cast<const f32x2*>(q  + 2 * (size_t)i);
        const f32x2 qdv = *reinterpret_cast<const f32x2*>(qd + 2 * (size_t)i);
        const float q0 = qv.x,  q1 = qv.y;
        const float qd0 = qdv.x, qd1 = qdv.y;

        float s0, c0, s01, c01;
        __sincosf(q0, &s0, &c0);          // v_sin_f32 / v_cos_f32
        __sincosf(q0 - q1, &s01, &c01);
        const float s1 = __sinf(q1);

        // --- Gq ---
        f32x2 gv; gv.x = KG1 * s0; gv.y = KG2 * s1;
        *reinterpret_cast<f32x2*>(outG + 2 * (size_t)i) = gv;

        // --- Cmat ---
        const float c12 = -KC * s01 * qd1;
        const float c21 =  KC * s01 * qd0;
        f32x4 cv; cv.x = 0.0f; cv.y = c12; cv.z = c21; cv.w = 0.0f;
        *reinterpret_cast<f32x4*>(outC + 4 * (size_t)i) = cv;

        // --- Mmat ---
        const float m12 = KC * c01;
        f32x4 mv; mv.x = M11; mv.y = m12; mv.z = m12; mv.w = M22;
        *reinterpret_cast<f32x4*>(outM + 4 * (size_t)i) = mv;

        // --- Rmat (stage to LDS, output layout) ---
        const float RVlat = 0.05f  * __cosf(0.8f  * q1 - PH_VLAT);
        const float RBF   = -0.038f * __cosf(q1 - PH_BF);
        const float RRF_h = 0.053f * __cosf(q0 - PH_RFH);
        const float RRF_k = 0.053f * __cosf(0.55f * q1 - PH_RFK);
        const float RST_h = -0.07f * __cosf(q0 - PH_STH);
        const float RST_k = -0.04f * __cosf(q1 - PH_STK);
        const float RIl   = 0.045f * __cosf(0.6f  * q0 - PH_IL);
        const float RGM   = -0.06f * __cosf(0.75f * q0 - PH_GM);
        const float RMG   = -0.038f * __cosf(0.7f  * q1 - PH_MG);

        float* lr = ldsR + (size_t)tid * 14;
        lr[0]  = RIl;   lr[1]  = RGM;   lr[2]  = RRF_h; lr[3]  = RST_h;
        lr[4]  = 0.0f;  lr[5]  = 0.0f;  lr[6]  = 0.0f;
        lr[7]  = 0.0f;  lr[8]  = 0.0f;
        lr[9]  = RRF_k; lr[10] = RST_k; lr[11] = RVlat; lr[12] = RBF; lr[13] = RMG;

        // --- L (stage to LDS, output layout) ---
        const float dq01 = q1 - q0;
        const float LIl  = 0.094f - 0.035f * (q0 - HALF_PI);
        const float LGM  = 0.127f + 0.04f  * (q0 - HALF_PI);
        const float LRF  = 0.06f + __builtin_amdgcn_sqrtf(LRF_SQ + LRF_2LH * c0)
                           - LRF_BASE - RKNEE * dq01;
        const float LST  = 0.055f + 0.05f * (q0 - HALF_PI) + RKNEE * dq01;
        const float Lvl  = 0.046f - RKNEE * dq01;   // 0.046 + RKNEE*(q0-q1)
        const float Lbf  = 0.139f + RKNEE * dq01;
        const float LMG  = 0.055f + RKNEE * dq01;

        float* ll = ldsL + (size_t)tid * 7;
        ll[0] = blendf(LIl);
        ll[1] = blendf(LGM);
        ll[2] = blendf(LRF);
        ll[3] = blendf(LST);
        ll[4] = blendf(Lvl);
        ll[5] = blendf(Lbf);
        ll[6] = blendf(LMG);
    }

    // Same-wave LDS ordering: reads below are program-order after writes above;
    // compiler inserts lgkmcnt waits (aliasing on the same __shared__ arrays).
    __builtin_amdgcn_wave_barrier();

    // --- wave-local vectorized flush (no block barrier) ---
    const int nrows = min(BLOCK, B - r0);
    const int wbase = wave * 64;                      // this wave's first row in block
    const int nw    = min(64, max(0, nrows - wbase)); // rows this wave staged

    if (nw > 0) {
        {
            const int nRe = nw * 14;
            const int nR4 = nRe >> 2;
            const f32x4* s4 = reinterpret_cast<const f32x4*>(ldsR + (size_t)wbase * 14);
            f32x4* d4 = reinterpret_cast<f32x4*>(outR + (size_t)(r0 + wbase) * 14);
            for (int j = lane; j < nR4; j += 64) d4[j] = s4[j];
            for (int e = (nR4 << 2) + lane; e < nRe; e += 64)
                outR[(size_t)(r0 + wbase) * 14 + e] = ldsR[(size_t)wbase * 14 + e];
        }
        {
            const int nLe = nw * 7;
            const int nL4 = nLe >> 2;
            const f32x4* s4 = reinterpret_cast<const f32x4*>(ldsL + (size_t)wbase * 7);
            f32x4* d4 = reinterpret_cast<f32x4*>(outL + (size_t)(r0 + wbase) * 7);
            for (int j = lane; j < nL4; j += 64) d4[j] = s4[j];
            for (int e = (nL4 << 2) + lane; e < nLe; e += 64)
                outL[(size_t)(r0 + wbase) * 7 + e] = ldsL[(size_t)wbase * 7 + e];
        }
    }

    // --- Adot = (U - A) / TACT1, fused elementwise phase (float4) ---
    {
        const long long n = 7LL * B;
        const int n4 = (int)(n >> 2);
        const f32x4* __restrict__ A4 = reinterpret_cast<const f32x4*>(A);
        const f32x4* __restrict__ U4 = reinterpret_cast<const f32x4*>(U);
        f32x4* __restrict__ Ad4 = reinterpret_cast<f32x4*>(outAd);
        const int stride = (int)gridDim.x * BLOCK;
        for (int idx = r0 + tid; idx < n4; idx += stride) {
            const f32x4 a = A4[idx];
            const f32x4 u = U4[idx];
            f32x4 d = (u - a) * INV_TACT;
            Ad4[idx] = d;
        }
        // scalar tail (B not multiple of 4)
        for (long long idx = 4LL * n4 + (r0 + tid); idx < n; idx += stride) {
            outAd[idx] = (U[idx] - A[idx]) * INV_TACT;
        }
    }
}

}  // namespace

extern "C" void kernel_launch(void* const* d_in, const int* in_sizes, int n_in,
                              void* d_out, int out_size, void* d_ws, size_t ws_size,
                              hipStream_t stream) {
    const float* q  = (const float*)d_in[0];
    const float* qd = (const float*)d_in[1];
    const float* A  = (const float*)d_in[2];
    const float* U  = (const float*)d_in[3];
    float* out = (float*)d_out;

    const int B = in_sizes[0] / 2;
    const int grid = (B + BLOCK - 1) / BLOCK;

    hipLaunchKernelGGL(crazyleg_kernel, dim3(grid), dim3(BLOCK), 0, stream,
                       q, qd, A, U, out, B);
}

// Round 7
// 37.377 us; speedup vs baseline: 1.0855x; 1.0288x over previous
//
#include <hip/hip_runtime.h>
#include <math.h>

namespace {

constexpr int BLOCK = 256;

typedef float f32x2 __attribute__((ext_vector_type(2)));
typedef float f32x4 __attribute__((ext_vector_type(4)));

constexpr double PI_D = 3.14159265358979323846;
constexpr double RAD = PI_D / 180.0;

// model constants (computed in double at compile time, truncated to f32)
constexpr float KG1 = (float)(-(9.1 * 0.15 + (3.6 + 1.5) * 0.39) * 9.81);   // -32.90274
constexpr float KG2 = (float)(-(3.6 * 0.2 + 1.5 * 0.43) * 9.81);            // -13.39065
constexpr float KC  = (float)(3.6 * 0.39 * 0.2 + 1.5 * 0.39 * 0.43);        // 0.53235
constexpr float M11 = (float)(0.112007 + 9.1 * 0.15 * 0.15 + (3.6 + 1.5) * 0.39 * 0.39); // 1.092467
constexpr float M22 = (float)(0.0591636 + 3.6 * 0.2 * 0.2 + 1.5 * 0.43 * 0.43);          // 0.4805136
constexpr float HALF_PI = (float)(PI_D / 2.0);

// cos(k*(x - phi)) = cos(k*x - k*phi): fused phases
constexpr float PH_VLAT = (float)(0.8 * 100.0 * RAD);
constexpr float PH_BF   = (float)(65.0 * RAD);
constexpr float PH_RFH  = (float)(127.0 * RAD);
constexpr float PH_RFK  = (float)(0.55 * 100.0 * RAD);
constexpr float PH_STH  = (float)(122.0 * RAD);
constexpr float PH_STK  = (float)(85.0 * RAD);
constexpr float PH_IL   = (float)(0.6 * 140.0 * RAD);
constexpr float PH_GM   = (float)(0.75 * 90.0 * RAD);
constexpr float PH_MG   = (float)(0.7 * 50.0 * RAD);

constexpr float LRF_SQ  = (float)(0.39 * 0.39 + 0.03 * 0.03);   // 0.1530
constexpr float LRF_2LH = (float)(2.0 * 0.39 * 0.03);           // 0.0234
constexpr float LRF_BASE = 0.39115214431f;                      // sqrt(0.1530)
constexpr float RKNEE = 0.03f;
constexpr float INV_TACT = (float)(1.0 / 0.12);

__device__ __forceinline__ float blendf(float x) {
    // s = 0.95 * sigmoid(100*(x-0.07)); x*s + (1-s)*0.05
    float t = 100.0f * (x - 0.07f);
    float e = __expf(-t);                              // v_exp_f32
    float s = 0.95f * __builtin_amdgcn_rcpf(1.0f + e); // v_rcp_f32
    return x * s + (1.0f - s) * 0.05f;
}

__global__ __launch_bounds__(BLOCK) void crazyleg_kernel(
    const float* __restrict__ q,
    const float* __restrict__ qd,
    const float* __restrict__ A,
    const float* __restrict__ U,
    float* __restrict__ out,
    int B)
{
    // Wave-local staging: each 64-lane wave stages its own 64 rows of R/L in
    // LDS (output layout, no padding) and flushes them itself -> NO s_barrier.
    //   write stride 14: gcd(14,32)=2 -> 2-way (free, m136); stride 7: odd -> clean
    //   flush: dense ds_read_b128 -> conflict-free
    // NOTE: no nontemporal hints anywhere — measured +2.3us regression (R5)
    // from nt loads; default cache path wins for streaming on gfx950.
    // R7: T14-style async split for the Adot phase — issue A/U loads early
    // (iter0 at kernel top, iter1 before the flush), consume after the flush,
    // hiding HBM latency under the trig/store phases.
    __shared__ __align__(16) float ldsR[BLOCK * 14];
    __shared__ __align__(16) float ldsL[BLOCK * 7];

    const int tid  = (int)threadIdx.x;
    const int wave = tid >> 6;
    const int lane = tid & 63;
    const int r0   = (int)blockIdx.x * BLOCK;
    const int i    = r0 + tid;

    float* __restrict__ outG  = out;
    float* __restrict__ outC  = out + (size_t)2  * B;
    float* __restrict__ outM  = out + (size_t)6  * B;
    float* __restrict__ outR  = out + (size_t)10 * B;
    float* __restrict__ outL  = out + (size_t)24 * B;
    float* __restrict__ outAd = out + (size_t)31 * B;

    // ---- Adot prefetch setup ----
    const long long n = 7LL * B;
    const int n4 = (int)(n >> 2);                 // # of f32x4 elements
    const int stride = (int)gridDim.x * BLOCK;
    const f32x4* __restrict__ A4 = reinterpret_cast<const f32x4*>(A);
    const f32x4* __restrict__ U4 = reinterpret_cast<const f32x4*>(U);
    f32x4* __restrict__ Ad4 = reinterpret_cast<f32x4*>(outAd);

    const int idx0 = r0 + tid;
    const bool have0 = idx0 < n4;                 // true for all threads when B=1e6
    f32x4 a0, u0;
    if (have0) { a0 = A4[idx0]; u0 = U4[idx0]; }  // ISSUE EARLY (consumed after flush)

    if (i < B) {
        const f32x2 qv  = *reinterpret_cast<const f32x2*>(q  + 2 * (size_t)i);
        const f32x2 qdv = *reinterpret_cast<const f32x2*>(qd + 2 * (size_t)i);
        const float q0 = qv.x,  q1 = qv.y;
        const float qd0 = qdv.x, qd1 = qdv.y;

        float s0, c0, s01, c01;
        __sincosf(q0, &s0, &c0);          // v_sin_f32 / v_cos_f32
        __sincosf(q0 - q1, &s01, &c01);
        const float s1 = __sinf(q1);

        // --- Gq ---
        f32x2 gv; gv.x = KG1 * s0; gv.y = KG2 * s1;
        *reinterpret_cast<f32x2*>(outG + 2 * (size_t)i) = gv;

        // --- Cmat ---
        const float c12 = -KC * s01 * qd1;
        const float c21 =  KC * s01 * qd0;
        f32x4 cv; cv.x = 0.0f; cv.y = c12; cv.z = c21; cv.w = 0.0f;
        *reinterpret_cast<f32x4*>(outC + 4 * (size_t)i) = cv;

        // --- Mmat ---
        const float m12 = KC * c01;
        f32x4 mv; mv.x = M11; mv.y = m12; mv.z = m12; mv.w = M22;
        *reinterpret_cast<f32x4*>(outM + 4 * (size_t)i) = mv;

        // --- Rmat (stage to LDS, output layout) ---
        const float RVlat = 0.05f  * __cosf(0.8f  * q1 - PH_VLAT);
        const float RBF   = -0.038f * __cosf(q1 - PH_BF);
        const float RRF_h = 0.053f * __cosf(q0 - PH_RFH);
        const float RRF_k = 0.053f * __cosf(0.55f * q1 - PH_RFK);
        const float RST_h = -0.07f * __cosf(q0 - PH_STH);
        const float RST_k = -0.04f * __cosf(q1 - PH_STK);
        const float RIl   = 0.045f * __cosf(0.6f  * q0 - PH_IL);
        const float RGM   = -0.06f * __cosf(0.75f * q0 - PH_GM);
        const float RMG   = -0.038f * __cosf(0.7f  * q1 - PH_MG);

        float* lr = ldsR + (size_t)tid * 14;
        lr[0]  = RIl;   lr[1]  = RGM;   lr[2]  = RRF_h; lr[3]  = RST_h;
        lr[4]  = 0.0f;  lr[5]  = 0.0f;  lr[6]  = 0.0f;
        lr[7]  = 0.0f;  lr[8]  = 0.0f;
        lr[9]  = RRF_k; lr[10] = RST_k; lr[11] = RVlat; lr[12] = RBF; lr[13] = RMG;

        // --- L (stage to LDS, output layout) ---
        const float dq01 = q1 - q0;
        const float LIl  = 0.094f - 0.035f * (q0 - HALF_PI);
        const float LGM  = 0.127f + 0.04f  * (q0 - HALF_PI);
        const float LRF  = 0.06f + __builtin_amdgcn_sqrtf(LRF_SQ + LRF_2LH * c0)
                           - LRF_BASE - RKNEE * dq01;
        const float LST  = 0.055f + 0.05f * (q0 - HALF_PI) + RKNEE * dq01;
        const float Lvl  = 0.046f - RKNEE * dq01;   // 0.046 + RKNEE*(q0-q1)
        const float Lbf  = 0.139f + RKNEE * dq01;
        const float LMG  = 0.055f + RKNEE * dq01;

        float* ll = ldsL + (size_t)tid * 7;
        ll[0] = blendf(LIl);
        ll[1] = blendf(LGM);
        ll[2] = blendf(LRF);
        ll[3] = blendf(LST);
        ll[4] = blendf(Lvl);
        ll[5] = blendf(Lbf);
        ll[6] = blendf(LMG);
    }

    // --- Adot iter1: ISSUE loads before the flush, consume after it ---
    const int idx1 = idx0 + stride;
    const bool have1 = idx1 < n4;
    f32x4 a1, u1;
    if (have1) { a1 = A4[idx1]; u1 = U4[idx1]; }

    // Same-wave LDS ordering: reads below are program-order after writes above;
    // compiler inserts lgkmcnt waits (aliasing on the same __shared__ arrays).
    __builtin_amdgcn_wave_barrier();

    // --- wave-local vectorized flush (no block barrier) ---
    const int nrows = min(BLOCK, B - r0);
    const int wbase = wave * 64;                      // this wave's first row in block
    const int nw    = min(64, max(0, nrows - wbase)); // rows this wave staged

    if (nw > 0) {
        {
            const int nRe = nw * 14;
            const int nR4 = nRe >> 2;
            const f32x4* s4 = reinterpret_cast<const f32x4*>(ldsR + (size_t)wbase * 14);
            f32x4* d4 = reinterpret_cast<f32x4*>(outR + (size_t)(r0 + wbase) * 14);
            for (int j = lane; j < nR4; j += 64) d4[j] = s4[j];
            for (int e = (nR4 << 2) + lane; e < nRe; e += 64)
                outR[(size_t)(r0 + wbase) * 14 + e] = ldsR[(size_t)wbase * 14 + e];
        }
        {
            const int nLe = nw * 7;
            const int nL4 = nLe >> 2;
            const f32x4* s4 = reinterpret_cast<const f32x4*>(ldsL + (size_t)wbase * 7);
            f32x4* d4 = reinterpret_cast<f32x4*>(outL + (size_t)(r0 + wbase) * 7);
            for (int j = lane; j < nL4; j += 64) d4[j] = s4[j];
            for (int e = (nL4 << 2) + lane; e < nLe; e += 64)
                outL[(size_t)(r0 + wbase) * 7 + e] = ldsL[(size_t)wbase * 7 + e];
        }
    }

    // --- Adot: consume prefetched iterations, then any remainder ---
    if (have0) Ad4[idx0] = (u0 - a0) * INV_TACT;
    if (have1) Ad4[idx1] = (u1 - a1) * INV_TACT;
    for (int idx = idx0 + 2 * stride; idx < n4; idx += stride) {
        const f32x4 a = A4[idx];
        const f32x4 u = U4[idx];
        Ad4[idx] = (u - a) * INV_TACT;
    }
    // scalar tail (7*B not multiple of 4 — empty for B=1e6, kept for generality)
    for (long long idx = 4LL * n4 + idx0; idx < n; idx += stride) {
        outAd[idx] = (U[idx] - A[idx]) * INV_TACT;
    }
}

}  // namespace

extern "C" void kernel_launch(void* const* d_in, const int* in_sizes, int n_in,
                              void* d_out, int out_size, void* d_ws, size_t ws_size,
                              hipStream_t stream) {
    const float* q  = (const float*)d_in[0];
    const float* qd = (const float*)d_in[1];
    const float* A  = (const float*)d_in[2];
    const float* U  = (const float*)d_in[3];
    float* out = (float*)d_out;

    const int B = in_sizes[0] / 2;
    const int grid = (B + BLOCK - 1) / BLOCK;

    hipLaunchKernelGGL(crazyleg_kernel, dim3(grid), dim3(BLOCK), 0, stream,
                       q, qd, A, U, out, B);
}